// Round 7
// baseline (353.592 us; speedup 1.0000x reference)
//
#include <hip/hip_runtime.h>
#include <hip/hip_fp16.h>

#define NN 100000
#define EE 600000
#define XSB 288          // bf16 feature row stride (262 used, 64B-aligned rows)
#define SCAN_B 2048

typedef __attribute__((ext_vector_type(8))) short s16x8;
typedef __attribute__((ext_vector_type(4))) float f32x4;

__device__ inline unsigned short f2b(float f) {   // fp32 -> bf16 RNE
    unsigned u = __float_as_uint(f);
    u += 0x7fffu + ((u >> 16) & 1u);
    return (unsigned short)(u >> 16);
}

// wt layout: [KP/32][192][32] (k-chunk, col, k-within-chunk), zero-padded k>=fin.
// cols 0-63 = lin, 64-127 = src, 128-191 = pos. (a_dst dead: softmax shift-invariance)
__device__ inline void wconv_elem(int idx, int fin,
                                  const float* wlin, const float* wsrc,
                                  const float* wpos, unsigned short* wt) {
    int ks = idx / 6144;          // 192*32
    int rem = idx - ks * 6144;
    int col = rem >> 5, kk = rem & 31;
    int k = ks * 32 + kk;
    float val = 0.f;
    if (k < fin) {
        int m = col >> 6, c = col & 63;
        const float* W = (m == 0) ? wlin : (m == 1) ? wsrc : wpos;
        val = W[k * 64 + c];
    }
    wt[idx] = f2b(val);
}

// ---------------- fused setup: init xb + weight conversions + degree histogram ----------------
// deg is zeroed by hipMemsetAsync BEFORE this kernel (stream-ordered graph edge).
#define O0 600000
#define O1 606144
#define O2 624576
#define O3 655296
#define O4 698304
#define O5 716736
#define O6 1316736

__global__ __launch_bounds__(256) void k_setup(
    const float* __restrict__ x, const int* __restrict__ ei,
    const float* __restrict__ wl0, const float* __restrict__ ws0, const float* __restrict__ wp0,
    const float* __restrict__ wl1, const float* __restrict__ ws1, const float* __restrict__ wp1,
    const float* __restrict__ wl2, const float* __restrict__ ws2, const float* __restrict__ wp2,
    const float* __restrict__ wl3, const float* __restrict__ ws3, const float* __restrict__ wp3,
    const float* __restrict__ w1,
    unsigned short* __restrict__ xb,
    unsigned short* __restrict__ wt0, unsigned short* __restrict__ wt1,
    unsigned short* __restrict__ wt2, unsigned short* __restrict__ wt3,
    unsigned short* __restrict__ w1t, int* __restrict__ deg) {
    int i = blockIdx.x * 256 + threadIdx.x;
    if (i < O0) {
        int n = i / 6, c = i - n * 6;
        xb[(size_t)n * XSB + c] = f2b(x[i]);
    } else if (i < O1) {
        wconv_elem(i - O0, 6, wl0, ws0, wp0, wt0);
    } else if (i < O2) {
        wconv_elem(i - O1, 70, wl1, ws1, wp1, wt1);
    } else if (i < O3) {
        wconv_elem(i - O2, 134, wl2, ws2, wp2, wt2);
    } else if (i < O4) {
        wconv_elem(i - O3, 198, wl3, ws3, wp3, wt3);
    } else if (i < O5) {
        int idx = i - O4;                 // 64*288
        int col = idx / 288, k = idx - col * 288;
        w1t[idx] = f2b((k < 262) ? w1[k * 64 + col] : 0.f);
    } else if (i < O6) {
        atomicAdd(&deg[ei[EE + (i - O5)]], 1);   // histogram of dst degrees
    }
}

// ---------------- CSR build ----------------

__global__ void k_scan1(const int* __restrict__ deg, int* __restrict__ rowptr,
                        int* __restrict__ bsum) {
    __shared__ int sh[256];
    int b = blockIdx.x, t = threadIdx.x;
    int base = b * SCAN_B + t * 8;
    int vals[8];
    int s = 0;
#pragma unroll
    for (int j = 0; j < 8; j++) {
        int i = base + j;
        int d = (i < NN) ? deg[i] : 0;
        s += d;
        vals[j] = s;
    }
    sh[t] = s;
    __syncthreads();
    for (int off = 1; off < 256; off <<= 1) {
        int vv = (t >= off) ? sh[t - off] : 0;
        __syncthreads();
        sh[t] += vv;
        __syncthreads();
    }
    int excl = (t > 0) ? sh[t - 1] : 0;
#pragma unroll
    for (int j = 0; j < 8; j++) {
        int i = base + j;
        if (i < NN) rowptr[i + 1] = vals[j] + excl;
    }
    if (t == 255) bsum[b] = sh[255];     // raw per-block total
}

// merged scan2+scan3: each block wave-reduces its own prefix of bsum (nb<=64)
__global__ void k_scan3m(const int* __restrict__ deg, int* __restrict__ rowptr,
                         const int* __restrict__ bsum, int* __restrict__ cursor) {
    __shared__ int soff;
    int b = blockIdx.x, t = threadIdx.x;
    if (t < 64) {
        int v = (t < b) ? bsum[t] : 0;   // nb = 49 <= 64
#pragma unroll
        for (int m = 1; m < 64; m <<= 1) v += __shfl_xor(v, m);
        if (t == 0) soff = v;
    }
    __syncthreads();
    int off = soff;
    int base = b * SCAN_B + t * 8;
#pragma unroll
    for (int j = 0; j < 8; j++) {
        int i = base + j;
        if (i < NN) {
            int incl = rowptr[i + 1] + off;
            rowptr[i + 1] = incl;
            cursor[i] = incl - deg[i];
        }
    }
    if (b == 0 && t == 0) rowptr[0] = 0;
}

__global__ void k_scatter(const int* __restrict__ ei, int* __restrict__ cursor,
                          int* __restrict__ csrc) {
    int e = blockIdx.x * 256 + threadIdx.x;
    if (e < EE) {
        int d = ei[EE + e];
        int pos = atomicAdd(&cursor[d], 1);
        csrc[pos] = ei[e];
    }
}

// ---------------- MFMA 3-way projection, LDS-staged weights ----------------
// Block: 256 thr = 4 waves, 128 rows/block (wave owns 32 rows = 2 A-frags).
// Per 32-k chunk: stage 192x32 bf16 W tile (12KB) in LDS; 24 MFMAs/wave.
// Epilogue: vg[node][c] = half2(a_src+p, h-p) ; qh[node][c] = half(p + b_pos).

template <int KP>
__global__ __launch_bounds__(256) void k_projm(
    const unsigned short* __restrict__ xb, const unsigned short* __restrict__ wt,
    const float* __restrict__ bpos,
    __half2* __restrict__ vg, __half* __restrict__ qh) {
    __shared__ short wl[192 * 32];
    const int t = threadIdx.x;
    const int w = t >> 6, l = t & 63;
    const int lo = l & 15, hi = l >> 4;
    const int row_w = blockIdx.x * 128 + w * 32;

    f32x4 acc[2][12];
#pragma unroll
    for (int a = 0; a < 2; a++)
#pragma unroll
        for (int i = 0; i < 12; i++) acc[a][i] = (f32x4)0.f;

    const unsigned short* arow0 = xb + (size_t)(row_w + lo) * XSB;
    const unsigned short* arow1 = xb + (size_t)(row_w + 16 + lo) * XSB;
#pragma unroll
    for (int ks = 0; ks < KP / 32; ks++) {
        __syncthreads();
        {
            const uint4* src = (const uint4*)wt + (size_t)ks * 768;
            uint4* dst = (uint4*)wl;
#pragma unroll
            for (int i = 0; i < 3; i++) dst[i * 256 + t] = src[i * 256 + t];
        }
        __syncthreads();
        s16x8 af0 = *(const s16x8*)(arow0 + ks * 32 + hi * 8);
        s16x8 af1 = *(const s16x8*)(arow1 + ks * 32 + hi * 8);
#pragma unroll
        for (int ct = 0; ct < 12; ct++) {
            s16x8 bf = *(const s16x8*)&wl[(ct * 16 + lo) * 32 + hi * 8];
            acc[0][ct] = __builtin_amdgcn_mfma_f32_16x16x32_bf16(af0, bf, acc[0][ct], 0, 0, 0);
            acc[1][ct] = __builtin_amdgcn_mfma_f32_16x16x32_bf16(af1, bf, acc[1][ct], 0, 0, 0);
        }
    }

#pragma unroll
    for (int tile = 0; tile < 2; tile++) {
#pragma unroll
        for (int r = 0; r < 4; r++) {
            int node = row_w + tile * 16 + hi * 4 + r;
            if (node < NN) {
#pragma unroll
                for (int j = 0; j < 4; j++) {
                    int c = j * 16 + lo;
                    float h  = acc[tile][0 + j][r];
                    float as = acc[tile][4 + j][r];
                    float p  = acc[tile][8 + j][r];
                    size_t o = (size_t)node * 64 + c;
                    vg[o] = __floats2half2_rn(as + p, h - p);
                    qh[o] = __float2half(p + bpos[c]);
                }
            }
        }
    }
}

// ---------------- MFMA MLP-1 (262->64) fused with MLP-2 (64->10) ----------------

__global__ __launch_bounds__(256) void k_mlp1f(
    const unsigned short* __restrict__ xb, const unsigned short* __restrict__ w1t,
    const float* __restrict__ b1, const float* __restrict__ w2,
    const float* __restrict__ b2, float* __restrict__ out) {
    __shared__ float w2l[64][10];
    __shared__ float b2l[10];
    __shared__ float b1l[64];
    for (int t = threadIdx.x; t < 714; t += 256) {
        if (t < 640) ((float*)w2l)[t] = w2[t];
        else if (t < 650) b2l[t - 640] = b2[t - 640];
        else b1l[t - 650] = b1[t - 650];
    }
    __syncthreads();

    const int w = threadIdx.x >> 6, l = threadIdx.x & 63;
    const int lo = l & 15, hi = l >> 4;
    const int row_w = blockIdx.x * 256 + w * 64;

    f32x4 acc[4][4];
#pragma unroll
    for (int a = 0; a < 4; a++)
#pragma unroll
        for (int b = 0; b < 4; b++) acc[a][b] = (f32x4)0.f;

#pragma unroll
    for (int ks = 0; ks < 9; ks++) {
        const int k0 = ks * 32 + hi * 8;
        s16x8 bf[4];
#pragma unroll
        for (int ct = 0; ct < 4; ct++)
            bf[ct] = *(const s16x8*)(w1t + (size_t)(ct * 16 + lo) * 288 + k0);
#pragma unroll
        for (int rt = 0; rt < 4; rt++) {
            s16x8 af = *(const s16x8*)(xb + (size_t)(row_w + rt * 16 + lo) * XSB + k0);
#pragma unroll
            for (int ct = 0; ct < 4; ct++)
                acc[rt][ct] = __builtin_amdgcn_mfma_f32_16x16x32_bf16(af, bf[ct], acc[rt][ct], 0, 0, 0);
        }
    }

    // epilogue: hid = acc + b1; out[node][o] = sum_c hid[c]*w2[c][o] + b2[o]
#pragma unroll
    for (int rt = 0; rt < 4; rt++) {
#pragma unroll
        for (int r = 0; r < 4; r++) {
            int node = row_w + rt * 16 + hi * 4 + r;
            float po[10];
#pragma unroll
            for (int o = 0; o < 10; o++) po[o] = 0.f;
#pragma unroll
            for (int ct = 0; ct < 4; ct++) {
                int c = ct * 16 + lo;
                float hv = acc[rt][ct][r] + b1l[c];
#pragma unroll
                for (int o = 0; o < 10; o++) po[o] = fmaf(hv, w2l[c][o], po[o]);
            }
#pragma unroll
            for (int m = 1; m < 16; m <<= 1)
#pragma unroll
                for (int o = 0; o < 10; o++) po[o] += __shfl_xor(po[o], m);
            if (lo == 0 && node < NN) {
                float* op = out + (size_t)node * 10;
#pragma unroll
                for (int o = 0; o < 5; o++)
                    *(float2*)(op + o * 2) = make_float2(po[o * 2] + b2l[o * 2],
                                                         po[o * 2 + 1] + b2l[o * 2 + 1]);
            }
        }
    }
}

// ---------------- edge aggregation: wave-per-node, no-max segment softmax ----------------
// Lane-half h handles edges of parity h; lane owns channels 2*(l&31), 2*(l&31)+1.
// Chunk of 16 edges: 8 independent 8B gathers in flight per lane-half.

template <int RELU>
__global__ __launch_bounds__(256) void k_edge(
    const uint2* __restrict__ vg,     // [node][32] uint2 = 64 channels of half2(v,g)
    const __half2* __restrict__ qh,   // [node][32] half2 = 64 channels of q
    const int* __restrict__ rowptr, const int* __restrict__ csrc,
    unsigned short* __restrict__ xb, int col) {
    int node = blockIdx.x * 4 + (threadIdx.x >> 6);
    int l = threadIdx.x & 63;
    int h = l >> 5, lp = l & 31;
    if (node >= NN) return;
    int b = rowptr[node], e = rowptr[node + 1];
    __half2 qraw = qh[(size_t)node * 32 + lp];   // prefetch (both halves, broadcast line)
    float d0 = 0.f, d1 = 0.f, s0 = 0.f, s1 = 0.f;
    for (int p0 = b; p0 < e; p0 += 16) {
        int cnt = e - p0;
        int sidx[8];
#pragma unroll
        for (int t = 0; t < 8; t++) {
            int pp = p0 + 2 * t + h;
            if (pp >= e) pp = e - 1;
            sidx[t] = csrc[pp];
        }
        uint2 gv[8];
#pragma unroll
        for (int t = 0; t < 8; t++)
            gv[t] = vg[(size_t)sidx[t] * 32 + lp];
#pragma unroll
        for (int t = 0; t < 8; t++) {
            bool ok = (2 * t + h) < cnt;
            float2 f0 = __half22float2(*(const __half2*)&gv[t].x);
            float2 f1 = __half22float2(*(const __half2*)&gv[t].y);
            float e0 = ok ? __expf(-f0.x) : 0.f;
            float e1 = ok ? __expf(-f1.x) : 0.f;
            d0 += e0; s0 = fmaf(e0, f0.y, s0);
            d1 += e1; s1 = fmaf(e1, f1.y, s1);
        }
    }
    d0 += __shfl_xor(d0, 32); d1 += __shfl_xor(d1, 32);
    s0 += __shfl_xor(s0, 32); s1 += __shfl_xor(s1, 32);
    if (h == 0) {
        float2 qf = __half22float2(qraw);
        float o0 = (s0 + qf.x * d0) / (d0 + 1e-16f);
        float o1 = (s1 + qf.y * d1) / (d1 + 1e-16f);
        if (RELU) {
            o0 = (o0 > 0.f) ? o0 : 0.01f * o0;
            o1 = (o1 > 0.f) ? o1 : 0.01f * o1;
        }
        unsigned pack = (unsigned)f2b(o0) | ((unsigned)f2b(o1) << 16);
        *(unsigned*)&xb[(size_t)node * XSB + col + 2 * lp] = pack;
    }
}

// ---------------- launch ----------------

extern "C" void kernel_launch(void* const* d_in, const int* in_sizes, int n_in,
                              void* d_out, int out_size, void* d_ws, size_t ws_size,
                              hipStream_t stream) {
    const float* x = (const float*)d_in[0];
    const int* ei = (const int*)d_in[1];
    const float* W[4][4];
    const float* BP[4];
    int base = 2;
    for (int l = 0; l < 4; l++) {
        for (int m = 0; m < 4; m++) W[l][m] = (const float*)d_in[base + m];
        BP[l] = (const float*)d_in[base + 4];
        base += 5;
    }
    const float* w1 = (const float*)d_in[22];
    const float* b1 = (const float*)d_in[23];
    const float* w2 = (const float*)d_in[24];
    const float* b2 = (const float*)d_in[25];

    char* wsp = (char*)d_ws;
    size_t off = 0;
    auto alloc = [&](size_t bytes) {
        void* p = wsp + off;
        off += (bytes + 255) & ~(size_t)255;
        return p;
    };
    unsigned short* xb = (unsigned short*)alloc((size_t)(NN + 256) * XSB * 2);
    __half2* vg = (__half2*)alloc((size_t)NN * 64 * 4);
    __half* qh = (__half*)alloc((size_t)NN * 64 * 2);
    int* deg = (int*)alloc((size_t)NN * 4);
    int* rowptr = (int*)alloc((size_t)(NN + 1) * 4);
    int* cursor = (int*)alloc((size_t)NN * 4);
    int* bsum = (int*)alloc(1024 * 4);
    int* csrc = (int*)alloc((size_t)EE * 4);
    const int KPv[4] = {32, 96, 160, 224};
    unsigned short* wt[4];
    for (int l = 0; l < 4; l++) wt[l] = (unsigned short*)alloc((size_t)192 * KPv[l] * 2);
    unsigned short* w1t = (unsigned short*)alloc((size_t)64 * 288 * 2);

    hipMemsetAsync(deg, 0, (size_t)NN * 4, stream);
    k_setup<<<(O6 + 255) / 256, 256, 0, stream>>>(
        x, ei, W[0][0], W[0][1], W[0][3], W[1][0], W[1][1], W[1][3],
        W[2][0], W[2][1], W[2][3], W[3][0], W[3][1], W[3][3], w1,
        xb, wt[0], wt[1], wt[2], wt[3], w1t, deg);

    int nb = (NN + SCAN_B - 1) / SCAN_B;  // 49
    k_scan1<<<nb, 256, 0, stream>>>(deg, rowptr, bsum);
    k_scan3m<<<nb, 256, 0, stream>>>(deg, rowptr, bsum, cursor);
    k_scatter<<<(EE + 255) / 256, 256, 0, stream>>>(ei, cursor, csrc);

    const int gProj = (NN + 127) / 128;  // 782
    const int gEdge = (NN + 3) / 4;      // 25000
    const uint2* vgu = (const uint2*)vg;
    const __half2* qh2 = (const __half2*)qh;

    k_projm<32><<<gProj, 256, 0, stream>>>(xb, wt[0], BP[0], vg, qh);
    k_edge<0><<<gEdge, 256, 0, stream>>>(vgu, qh2, rowptr, csrc, xb, 6);
    k_projm<96><<<gProj, 256, 0, stream>>>(xb, wt[1], BP[1], vg, qh);
    k_edge<1><<<gEdge, 256, 0, stream>>>(vgu, qh2, rowptr, csrc, xb, 70);
    k_projm<160><<<gProj, 256, 0, stream>>>(xb, wt[2], BP[2], vg, qh);
    k_edge<1><<<gEdge, 256, 0, stream>>>(vgu, qh2, rowptr, csrc, xb, 134);
    k_projm<224><<<gProj, 256, 0, stream>>>(xb, wt[3], BP[3], vg, qh);
    k_edge<1><<<gEdge, 256, 0, stream>>>(vgu, qh2, rowptr, csrc, xb, 198);

    k_mlp1f<<<(NN + 255) / 256, 256, 0, stream>>>(xb, w1t, b1, w2, b2, (float*)d_out);
}

// Round 8
// 330.426 us; speedup vs baseline: 1.0701x; 1.0701x over previous
//
#include <hip/hip_runtime.h>
#include <hip/hip_fp16.h>

#define NN 100000
#define EE 600000
#define XSB 288          // bf16 feature row stride (262 used, 64B-aligned rows)
#define SCAN_B 2048
#define LOG2E 1.44269504f

typedef __attribute__((ext_vector_type(8))) short s16x8;
typedef __attribute__((ext_vector_type(4))) float f32x4;

__device__ inline unsigned short f2b(float f) {   // fp32 -> bf16 RNE
    unsigned u = __float_as_uint(f);
    u += 0x7fffu + ((u >> 16) & 1u);
    return (unsigned short)(u >> 16);
}

// wt layout: [KP/32][192][32] (k-chunk, col, k-within-chunk), zero-padded k>=fin.
// cols 0-63 = lin, 64-127 = src, 128-191 = pos. (a_dst dead: softmax shift-invariance)
__device__ inline void wconv_elem(int idx, int fin,
                                  const float* wlin, const float* wsrc,
                                  const float* wpos, unsigned short* wt) {
    int ks = idx / 6144;          // 192*32
    int rem = idx - ks * 6144;
    int col = rem >> 5, kk = rem & 31;
    int k = ks * 32 + kk;
    float val = 0.f;
    if (k < fin) {
        int m = col >> 6, c = col & 63;
        const float* W = (m == 0) ? wlin : (m == 1) ? wsrc : wpos;
        val = W[k * 64 + c];
    }
    wt[idx] = f2b(val);
}

// ---------------- fused setup: init xb + weight conversions + degree histogram + dummy row ----
// deg is zeroed by hipMemsetAsync BEFORE this kernel (stream-ordered).
#define O0 600000
#define O1 606144
#define O2 624576
#define O3 655296
#define O4 698304
#define O5 716736
#define O6 1316736
#define O7 1316800       // +64: dummy vg row NN = (v=-inf, g=0) -> exp2 contributes 0

__global__ __launch_bounds__(256) void k_setup(
    const float* __restrict__ x, const int* __restrict__ ei,
    const float* __restrict__ wl0, const float* __restrict__ ws0, const float* __restrict__ wp0,
    const float* __restrict__ wl1, const float* __restrict__ ws1, const float* __restrict__ wp1,
    const float* __restrict__ wl2, const float* __restrict__ ws2, const float* __restrict__ wp2,
    const float* __restrict__ wl3, const float* __restrict__ ws3, const float* __restrict__ wp3,
    const float* __restrict__ w1,
    unsigned short* __restrict__ xb,
    unsigned short* __restrict__ wt0, unsigned short* __restrict__ wt1,
    unsigned short* __restrict__ wt2, unsigned short* __restrict__ wt3,
    unsigned short* __restrict__ w1t, int* __restrict__ deg,
    unsigned* __restrict__ vgu) {
    int i = blockIdx.x * 256 + threadIdx.x;
    if (i < O0) {
        int n = i / 6, c = i - n * 6;
        xb[(size_t)n * XSB + c] = f2b(x[i]);
    } else if (i < O1) {
        wconv_elem(i - O0, 6, wl0, ws0, wp0, wt0);
    } else if (i < O2) {
        wconv_elem(i - O1, 70, wl1, ws1, wp1, wt1);
    } else if (i < O3) {
        wconv_elem(i - O2, 134, wl2, ws2, wp2, wt2);
    } else if (i < O4) {
        wconv_elem(i - O3, 198, wl3, ws3, wp3, wt3);
    } else if (i < O5) {
        int idx = i - O4;                 // 64*288
        int col = idx / 288, k = idx - col * 288;
        w1t[idx] = f2b((k < 262) ? w1[k * 64 + col] : 0.f);
    } else if (i < O6) {
        atomicAdd(&deg[ei[EE + (i - O5)]], 1);   // dst-degree histogram
    } else if (i < O7) {
        vgu[(size_t)NN * 64 + (i - O6)] = 0x0000FC00u;  // half2(-inf, 0)
    }
}

// ---------------- CSR build ----------------

__global__ void k_scan1(const int* __restrict__ deg, int* __restrict__ rowptr,
                        int* __restrict__ bsum) {
    __shared__ int sh[256];
    int b = blockIdx.x, t = threadIdx.x;
    int base = b * SCAN_B + t * 8;
    int vals[8];
    int s = 0;
#pragma unroll
    for (int j = 0; j < 8; j++) {
        int i = base + j;
        int d = (i < NN) ? deg[i] : 0;
        s += d;
        vals[j] = s;
    }
    sh[t] = s;
    __syncthreads();
    for (int off = 1; off < 256; off <<= 1) {
        int vv = (t >= off) ? sh[t - off] : 0;
        __syncthreads();
        sh[t] += vv;
        __syncthreads();
    }
    int excl = (t > 0) ? sh[t - 1] : 0;
#pragma unroll
    for (int j = 0; j < 8; j++) {
        int i = base + j;
        if (i < NN) rowptr[i + 1] = vals[j] + excl;
    }
    if (t == 255) bsum[b] = sh[255];     // raw per-block total
}

// merged scan2+scan3: each block wave-reduces its own prefix of bsum (nb<=64)
__global__ void k_scan3m(const int* __restrict__ deg, int* __restrict__ rowptr,
                         const int* __restrict__ bsum, int* __restrict__ cursor) {
    __shared__ int soff;
    int b = blockIdx.x, t = threadIdx.x;
    if (t < 64) {
        int v = (t < b) ? bsum[t] : 0;   // nb = 49 <= 64
#pragma unroll
        for (int m = 1; m < 64; m <<= 1) v += __shfl_xor(v, m);
        if (t == 0) soff = v;
    }
    __syncthreads();
    int off = soff;
    int base = b * SCAN_B + t * 8;
#pragma unroll
    for (int j = 0; j < 8; j++) {
        int i = base + j;
        if (i < NN) {
            int incl = rowptr[i + 1] + off;
            rowptr[i + 1] = incl;
            cursor[i] = incl - deg[i];
        }
    }
    if (b == 0 && t == 0) rowptr[0] = 0;
}

__global__ void k_scatter(const int* __restrict__ ei, int* __restrict__ cursor,
                          int* __restrict__ csrc) {
    int e = blockIdx.x * 256 + threadIdx.x;
    if (e < EE) {
        int d = ei[EE + e];
        int pos = atomicAdd(&cursor[d], 1);
        csrc[pos] = ei[e];
    }
}

// ---------------- MFMA 3-way projection, LDS-staged weights ----------------
// Epilogue: vg[node][c] = half2( -(a_src+p)*log2(e), h-p ) ; qh[node][c] = half(p + b_pos).
// (log2e/negation folded in so the edge kernel runs a bare v_exp_f32.)

template <int KP>
__global__ __launch_bounds__(256) void k_projm(
    const unsigned short* __restrict__ xb, const unsigned short* __restrict__ wt,
    const float* __restrict__ bpos,
    __half2* __restrict__ vg, __half* __restrict__ qh) {
    __shared__ short wl[192 * 32];
    const int t = threadIdx.x;
    const int w = t >> 6, l = t & 63;
    const int lo = l & 15, hi = l >> 4;
    const int row_w = blockIdx.x * 128 + w * 32;

    f32x4 acc[2][12];
#pragma unroll
    for (int a = 0; a < 2; a++)
#pragma unroll
        for (int i = 0; i < 12; i++) acc[a][i] = (f32x4)0.f;

    const unsigned short* arow0 = xb + (size_t)(row_w + lo) * XSB;
    const unsigned short* arow1 = xb + (size_t)(row_w + 16 + lo) * XSB;
#pragma unroll
    for (int ks = 0; ks < KP / 32; ks++) {
        __syncthreads();
        {
            const uint4* src = (const uint4*)wt + (size_t)ks * 768;
            uint4* dst = (uint4*)wl;
#pragma unroll
            for (int i = 0; i < 3; i++) dst[i * 256 + t] = src[i * 256 + t];
        }
        __syncthreads();
        s16x8 af0 = *(const s16x8*)(arow0 + ks * 32 + hi * 8);
        s16x8 af1 = *(const s16x8*)(arow1 + ks * 32 + hi * 8);
#pragma unroll
        for (int ct = 0; ct < 12; ct++) {
            s16x8 bf = *(const s16x8*)&wl[(ct * 16 + lo) * 32 + hi * 8];
            acc[0][ct] = __builtin_amdgcn_mfma_f32_16x16x32_bf16(af0, bf, acc[0][ct], 0, 0, 0);
            acc[1][ct] = __builtin_amdgcn_mfma_f32_16x16x32_bf16(af1, bf, acc[1][ct], 0, 0, 0);
        }
    }

#pragma unroll
    for (int tile = 0; tile < 2; tile++) {
#pragma unroll
        for (int r = 0; r < 4; r++) {
            int node = row_w + tile * 16 + hi * 4 + r;
            if (node < NN) {
#pragma unroll
                for (int j = 0; j < 4; j++) {
                    int c = j * 16 + lo;
                    float h  = acc[tile][0 + j][r];
                    float as = acc[tile][4 + j][r];
                    float p  = acc[tile][8 + j][r];
                    size_t o = (size_t)node * 64 + c;
                    vg[o] = __floats2half2_rn(-(as + p) * LOG2E, h - p);
                    qh[o] = __float2half(p + bpos[c]);
                }
            }
        }
    }
}

// ---------------- MFMA MLP-1 (262->64) fused with MLP-2 (64->10) ----------------

__global__ __launch_bounds__(256) void k_mlp1f(
    const unsigned short* __restrict__ xb, const unsigned short* __restrict__ w1t,
    const float* __restrict__ b1, const float* __restrict__ w2,
    const float* __restrict__ b2, float* __restrict__ out) {
    __shared__ float w2l[64][10];
    __shared__ float b2l[10];
    __shared__ float b1l[64];
    for (int t = threadIdx.x; t < 714; t += 256) {
        if (t < 640) ((float*)w2l)[t] = w2[t];
        else if (t < 650) b2l[t - 640] = b2[t - 640];
        else b1l[t - 650] = b1[t - 650];
    }
    __syncthreads();

    const int w = threadIdx.x >> 6, l = threadIdx.x & 63;
    const int lo = l & 15, hi = l >> 4;
    const int row_w = blockIdx.x * 256 + w * 64;

    f32x4 acc[4][4];
#pragma unroll
    for (int a = 0; a < 4; a++)
#pragma unroll
        for (int b = 0; b < 4; b++) acc[a][b] = (f32x4)0.f;

#pragma unroll
    for (int ks = 0; ks < 9; ks++) {
        const int k0 = ks * 32 + hi * 8;
        s16x8 bf[4];
#pragma unroll
        for (int ct = 0; ct < 4; ct++)
            bf[ct] = *(const s16x8*)(w1t + (size_t)(ct * 16 + lo) * 288 + k0);
#pragma unroll
        for (int rt = 0; rt < 4; rt++) {
            s16x8 af = *(const s16x8*)(xb + (size_t)(row_w + rt * 16 + lo) * XSB + k0);
#pragma unroll
            for (int ct = 0; ct < 4; ct++)
                acc[rt][ct] = __builtin_amdgcn_mfma_f32_16x16x32_bf16(af, bf[ct], acc[rt][ct], 0, 0, 0);
        }
    }

#pragma unroll
    for (int rt = 0; rt < 4; rt++) {
#pragma unroll
        for (int r = 0; r < 4; r++) {
            int node = row_w + rt * 16 + hi * 4 + r;
            float po[10];
#pragma unroll
            for (int o = 0; o < 10; o++) po[o] = 0.f;
#pragma unroll
            for (int ct = 0; ct < 4; ct++) {
                int c = ct * 16 + lo;
                float hv = acc[rt][ct][r] + b1l[c];
#pragma unroll
                for (int o = 0; o < 10; o++) po[o] = fmaf(hv, w2l[c][o], po[o]);
            }
#pragma unroll
            for (int m = 1; m < 16; m <<= 1)
#pragma unroll
                for (int o = 0; o < 10; o++) po[o] += __shfl_xor(po[o], m);
            if (lo == 0 && node < NN) {
                float* op = out + (size_t)node * 10;
#pragma unroll
                for (int o = 0; o < 5; o++)
                    *(float2*)(op + o * 2) = make_float2(po[o * 2] + b2l[o * 2],
                                                         po[o * 2 + 1] + b2l[o * 2 + 1]);
            }
        }
    }
}

// ---------------- edge aggregation: wave-per-node, 16 lanes per edge ----------------
// Lane group g = l>>4 handles edges p0+g, p0+4+g; lane lg = l&15 owns channels 4lg..4lg+3
// via one 16B uint4 gather. Clamped slots gather dummy row NN (v=-inf -> exp2=0): no
// per-channel masking. Reduce over 4 groups with shfl_xor(16|32).

template <int RELU>
__global__ __launch_bounds__(256) void k_edge(
    const uint4* __restrict__ vg,     // [NN+1][16] uint4 = 64 channels of half2(v', g)
    const uint2* __restrict__ qh,     // [NN][16] uint2 = 64 channels of half q
    const int* __restrict__ rowptr, const int* __restrict__ csrc,
    unsigned short* __restrict__ xb, int col) {
    int node = blockIdx.x * 4 + (threadIdx.x >> 6);
    int l = threadIdx.x & 63;
    int g = l >> 4, lg = l & 15;
    if (node >= NN) return;
    int b = rowptr[node], e = rowptr[node + 1];
    uint2 qr = qh[(size_t)node * 16 + lg];       // prefetch (broadcast across groups)
    float d[4] = {0.f, 0.f, 0.f, 0.f};
    float s[4] = {0.f, 0.f, 0.f, 0.f};
    for (int p0 = b; p0 < e; p0 += 8) {
        int pp0 = p0 + g, pp1 = p0 + 4 + g;
        int c0 = csrc[min(pp0, e - 1)];
        int c1 = csrc[min(pp1, e - 1)];
        int i0 = (pp0 < e) ? c0 : NN;
        int i1 = (pp1 < e) ? c1 : NN;
        uint4 r0 = vg[(size_t)i0 * 16 + lg];
        uint4 r1 = vg[(size_t)i1 * 16 + lg];
#pragma unroll
        for (int ch = 0; ch < 4; ch++) {
            float2 f = __half22float2(((const __half2*)&r0)[ch]);
            float ee = __builtin_amdgcn_exp2f(f.x);
            d[ch] += ee; s[ch] = fmaf(ee, f.y, s[ch]);
        }
#pragma unroll
        for (int ch = 0; ch < 4; ch++) {
            float2 f = __half22float2(((const __half2*)&r1)[ch]);
            float ee = __builtin_amdgcn_exp2f(f.x);
            d[ch] += ee; s[ch] = fmaf(ee, f.y, s[ch]);
        }
    }
#pragma unroll
    for (int ch = 0; ch < 4; ch++) {
        d[ch] += __shfl_xor(d[ch], 16); s[ch] += __shfl_xor(s[ch], 16);
        d[ch] += __shfl_xor(d[ch], 32); s[ch] += __shfl_xor(s[ch], 32);
    }
    if (g == 0) {
        float2 q01 = __half22float2(*(const __half2*)&qr.x);
        float2 q23 = __half22float2(*(const __half2*)&qr.y);
        float qv[4] = {q01.x, q01.y, q23.x, q23.y};
        float o[4];
#pragma unroll
        for (int ch = 0; ch < 4; ch++) {
            float v = (s[ch] + qv[ch] * d[ch]) / (d[ch] + 1e-16f);
            if (RELU) v = (v > 0.f) ? v : 0.01f * v;
            o[ch] = v;
        }
        unsigned short* dst = xb + (size_t)node * XSB + col + 4 * lg;
        *(unsigned*)(dst)     = (unsigned)f2b(o[0]) | ((unsigned)f2b(o[1]) << 16);
        *(unsigned*)(dst + 2) = (unsigned)f2b(o[2]) | ((unsigned)f2b(o[3]) << 16);
    }
}

// ---------------- launch ----------------

extern "C" void kernel_launch(void* const* d_in, const int* in_sizes, int n_in,
                              void* d_out, int out_size, void* d_ws, size_t ws_size,
                              hipStream_t stream) {
    const float* x = (const float*)d_in[0];
    const int* ei = (const int*)d_in[1];
    const float* W[4][4];
    const float* BP[4];
    int base = 2;
    for (int l = 0; l < 4; l++) {
        for (int m = 0; m < 4; m++) W[l][m] = (const float*)d_in[base + m];
        BP[l] = (const float*)d_in[base + 4];
        base += 5;
    }
    const float* w1 = (const float*)d_in[22];
    const float* b1 = (const float*)d_in[23];
    const float* w2 = (const float*)d_in[24];
    const float* b2 = (const float*)d_in[25];

    char* wsp = (char*)d_ws;
    size_t off = 0;
    auto alloc = [&](size_t bytes) {
        void* p = wsp + off;
        off += (bytes + 255) & ~(size_t)255;
        return p;
    };
    unsigned short* xb = (unsigned short*)alloc((size_t)(NN + 256) * XSB * 2);
    __half2* vg = (__half2*)alloc((size_t)(NN + 1) * 64 * 4);   // +1 dummy row
    __half* qh = (__half*)alloc((size_t)NN * 64 * 2);
    int* deg = (int*)alloc((size_t)NN * 4);
    int* rowptr = (int*)alloc((size_t)(NN + 1) * 4);
    int* cursor = (int*)alloc((size_t)NN * 4);
    int* bsum = (int*)alloc(1024 * 4);
    int* csrc = (int*)alloc((size_t)EE * 4);
    const int KPv[4] = {32, 96, 160, 224};
    unsigned short* wt[4];
    for (int l = 0; l < 4; l++) wt[l] = (unsigned short*)alloc((size_t)192 * KPv[l] * 2);
    unsigned short* w1t = (unsigned short*)alloc((size_t)64 * 288 * 2);

    hipMemsetAsync(deg, 0, (size_t)NN * 4, stream);
    k_setup<<<(O7 + 255) / 256, 256, 0, stream>>>(
        x, ei, W[0][0], W[0][1], W[0][3], W[1][0], W[1][1], W[1][3],
        W[2][0], W[2][1], W[2][3], W[3][0], W[3][1], W[3][3], w1,
        xb, wt[0], wt[1], wt[2], wt[3], w1t, deg, (unsigned*)vg);

    int nb = (NN + SCAN_B - 1) / SCAN_B;  // 49
    k_scan1<<<nb, 256, 0, stream>>>(deg, rowptr, bsum);
    k_scan3m<<<nb, 256, 0, stream>>>(deg, rowptr, bsum, cursor);
    k_scatter<<<(EE + 255) / 256, 256, 0, stream>>>(ei, cursor, csrc);

    const int gProj = (NN + 127) / 128;  // 782
    const int gEdge = (NN + 3) / 4;      // 25000
    const uint4* vgu = (const uint4*)vg;
    const uint2* qh2 = (const uint2*)qh;

    k_projm<32><<<gProj, 256, 0, stream>>>(xb, wt[0], BP[0], vg, qh);
    k_edge<0><<<gEdge, 256, 0, stream>>>(vgu, qh2, rowptr, csrc, xb, 6);
    k_projm<96><<<gProj, 256, 0, stream>>>(xb, wt[1], BP[1], vg, qh);
    k_edge<1><<<gEdge, 256, 0, stream>>>(vgu, qh2, rowptr, csrc, xb, 70);
    k_projm<160><<<gProj, 256, 0, stream>>>(xb, wt[2], BP[2], vg, qh);
    k_edge<1><<<gEdge, 256, 0, stream>>>(vgu, qh2, rowptr, csrc, xb, 134);
    k_projm<224><<<gProj, 256, 0, stream>>>(xb, wt[3], BP[3], vg, qh);
    k_edge<1><<<gEdge, 256, 0, stream>>>(vgu, qh2, rowptr, csrc, xb, 198);

    k_mlp1f<<<(NN + 255) / 256, 256, 0, stream>>>(xb, w1t, b1, w2, b2, (float*)d_out);
}

// Round 10
// 323.599 us; speedup vs baseline: 1.0927x; 1.0211x over previous
//
#include <hip/hip_runtime.h>
#include <hip/hip_fp16.h>

#define NN 100000
#define EE 600000
#define XSB 288          // bf16 feature row stride (262 used, 64B-aligned rows)
#define SCAN_B 2048
#define LOG2E 1.44269504f

typedef __attribute__((ext_vector_type(8))) short s16x8;
typedef __attribute__((ext_vector_type(4))) float f32x4;

__device__ inline unsigned short f2b(float f) {   // fp32 -> bf16 RNE
    unsigned u = __float_as_uint(f);
    u += 0x7fffu + ((u >> 16) & 1u);
    return (unsigned short)(u >> 16);
}

// wt layout: [KP/32][192][32] (k-chunk, col, k-within-chunk), zero-padded k>=fin.
// cols 0-63 = lin, 64-127 = src, 128-191 = pos. (a_dst dead: softmax shift-invariance)
__device__ inline void wconv_elem(int idx, int fin,
                                  const float* wlin, const float* wsrc,
                                  const float* wpos, unsigned short* wt) {
    int ks = idx / 6144;          // 192*32
    int rem = idx - ks * 6144;
    int col = rem >> 5, kk = rem & 31;
    int k = ks * 32 + kk;
    float val = 0.f;
    if (k < fin) {
        int m = col >> 6, c = col & 63;
        const float* W = (m == 0) ? wlin : (m == 1) ? wsrc : wpos;
        val = W[k * 64 + c];
    }
    wt[idx] = f2b(val);
}

// ---------------- fused setup: init xb + weight conversions + degree histogram + dummy row ----
// deg is zeroed by hipMemsetAsync BEFORE this kernel (stream-ordered).
#define O0 600000
#define O1 606144
#define O2 624576
#define O3 655296
#define O4 698304
#define O5 716736
#define O6 1316736
#define O7 1316800       // +64: dummy vg row NN = (P=0, PG=0) -> contributes nothing

__global__ __launch_bounds__(256) void k_setup(
    const float* __restrict__ x, const int* __restrict__ ei,
    const float* __restrict__ wl0, const float* __restrict__ ws0, const float* __restrict__ wp0,
    const float* __restrict__ wl1, const float* __restrict__ ws1, const float* __restrict__ wp1,
    const float* __restrict__ wl2, const float* __restrict__ ws2, const float* __restrict__ wp2,
    const float* __restrict__ wl3, const float* __restrict__ ws3, const float* __restrict__ wp3,
    const float* __restrict__ w1,
    unsigned short* __restrict__ xb,
    unsigned short* __restrict__ wt0, unsigned short* __restrict__ wt1,
    unsigned short* __restrict__ wt2, unsigned short* __restrict__ wt3,
    unsigned short* __restrict__ w1t, int* __restrict__ deg,
    unsigned* __restrict__ vgu) {
    int i = blockIdx.x * 256 + threadIdx.x;
    if (i < O0) {
        int n = i / 6, c = i - n * 6;
        xb[(size_t)n * XSB + c] = f2b(x[i]);
    } else if (i < O1) {
        wconv_elem(i - O0, 6, wl0, ws0, wp0, wt0);
    } else if (i < O2) {
        wconv_elem(i - O1, 70, wl1, ws1, wp1, wt1);
    } else if (i < O3) {
        wconv_elem(i - O2, 134, wl2, ws2, wp2, wt2);
    } else if (i < O4) {
        wconv_elem(i - O3, 198, wl3, ws3, wp3, wt3);
    } else if (i < O5) {
        int idx = i - O4;                 // 64*288
        int col = idx / 288, k = idx - col * 288;
        w1t[idx] = f2b((k < 262) ? w1[k * 64 + col] : 0.f);
    } else if (i < O6) {
        atomicAdd(&deg[ei[EE + (i - O5)]], 1);   // dst-degree histogram
    } else if (i < O7) {
        vgu[(size_t)NN * 64 + (i - O6)] = 0u;    // dummy row: (P,PG) = (0,0)
    }
}

// ---------------- CSR build ----------------

__global__ void k_scan1(const int* __restrict__ deg, int* __restrict__ rowptr,
                        int* __restrict__ bsum) {
    __shared__ int sh[256];
    int b = blockIdx.x, t = threadIdx.x;
    int base = b * SCAN_B + t * 8;
    int vals[8];
    int s = 0;
#pragma unroll
    for (int j = 0; j < 8; j++) {
        int i = base + j;
        int d = (i < NN) ? deg[i] : 0;
        s += d;
        vals[j] = s;
    }
    sh[t] = s;
    __syncthreads();
    for (int off = 1; off < 256; off <<= 1) {
        int vv = (t >= off) ? sh[t - off] : 0;
        __syncthreads();
        sh[t] += vv;
        __syncthreads();
    }
    int excl = (t > 0) ? sh[t - 1] : 0;
#pragma unroll
    for (int j = 0; j < 8; j++) {
        int i = base + j;
        if (i < NN) rowptr[i + 1] = vals[j] + excl;
    }
    if (t == 255) bsum[b] = sh[255];     // raw per-block total
}

// merged scan2+scan3: each block wave-reduces its own prefix of bsum (nb<=64)
__global__ void k_scan3m(const int* __restrict__ deg, int* __restrict__ rowptr,
                         const int* __restrict__ bsum, int* __restrict__ cursor) {
    __shared__ int soff;
    int b = blockIdx.x, t = threadIdx.x;
    if (t < 64) {
        int v = (t < b) ? bsum[t] : 0;   // nb = 49 <= 64
#pragma unroll
        for (int m = 1; m < 64; m <<= 1) v += __shfl_xor(v, m);
        if (t == 0) soff = v;
    }
    __syncthreads();
    int off = soff;
    int base = b * SCAN_B + t * 8;
#pragma unroll
    for (int j = 0; j < 8; j++) {
        int i = base + j;
        if (i < NN) {
            int incl = rowptr[i + 1] + off;
            rowptr[i + 1] = incl;
            cursor[i] = incl - deg[i];
        }
    }
    if (b == 0 && t == 0) rowptr[0] = 0;
}

__global__ void k_scatter(const int* __restrict__ ei, int* __restrict__ cursor,
                          int* __restrict__ csrc) {
    int e = blockIdx.x * 256 + threadIdx.x;
    if (e < EE) {
        int d = ei[EE + e];
        int pos = atomicAdd(&cursor[d], 1);
        csrc[pos] = ei[e];
    }
}

// ---------------- MFMA 3-way projection, LDS-staged weights ----------------
// The softmax numerator exp(-v) depends only on the SOURCE node, so precompute
// P = 2^(-(a_src+p)*log2e) and PG = P*(h-p), packed as TWO BF16 in one uint32
// (bf16 has fp32 exponent range: e^+-25 cannot overflow/underflow, unlike fp16).
// qh[node][c] = half(p + b_pos).

template <int KP>
__global__ __launch_bounds__(256) void k_projm(
    const unsigned short* __restrict__ xb, const unsigned short* __restrict__ wt,
    const float* __restrict__ bpos,
    unsigned* __restrict__ vg, __half* __restrict__ qh) {
    __shared__ short wl[192 * 32];
    const int t = threadIdx.x;
    const int w = t >> 6, l = t & 63;
    const int lo = l & 15, hi = l >> 4;
    const int row_w = blockIdx.x * 128 + w * 32;

    f32x4 acc[2][12];
#pragma unroll
    for (int a = 0; a < 2; a++)
#pragma unroll
        for (int i = 0; i < 12; i++) acc[a][i] = (f32x4)0.f;

    const unsigned short* arow0 = xb + (size_t)(row_w + lo) * XSB;
    const unsigned short* arow1 = xb + (size_t)(row_w + 16 + lo) * XSB;
#pragma unroll
    for (int ks = 0; ks < KP / 32; ks++) {
        __syncthreads();
        {
            const uint4* src = (const uint4*)wt + (size_t)ks * 768;
            uint4* dst = (uint4*)wl;
#pragma unroll
            for (int i = 0; i < 3; i++) dst[i * 256 + t] = src[i * 256 + t];
        }
        __syncthreads();
        s16x8 af0 = *(const s16x8*)(arow0 + ks * 32 + hi * 8);
        s16x8 af1 = *(const s16x8*)(arow1 + ks * 32 + hi * 8);
#pragma unroll
        for (int ct = 0; ct < 12; ct++) {
            s16x8 bf = *(const s16x8*)&wl[(ct * 16 + lo) * 32 + hi * 8];
            acc[0][ct] = __builtin_amdgcn_mfma_f32_16x16x32_bf16(af0, bf, acc[0][ct], 0, 0, 0);
            acc[1][ct] = __builtin_amdgcn_mfma_f32_16x16x32_bf16(af1, bf, acc[1][ct], 0, 0, 0);
        }
    }

#pragma unroll
    for (int tile = 0; tile < 2; tile++) {
#pragma unroll
        for (int r = 0; r < 4; r++) {
            int node = row_w + tile * 16 + hi * 4 + r;
            if (node < NN) {
#pragma unroll
                for (int j = 0; j < 4; j++) {
                    int c = j * 16 + lo;
                    float h  = acc[tile][0 + j][r];
                    float as = acc[tile][4 + j][r];
                    float p  = acc[tile][8 + j][r];
                    size_t o = (size_t)node * 64 + c;
                    float P = __builtin_amdgcn_exp2f(-(as + p) * LOG2E);
                    vg[o] = (unsigned)f2b(P) | ((unsigned)f2b(P * (h - p)) << 16);
                    qh[o] = __float2half(p + bpos[c]);
                }
            }
        }
    }
}

// ---------------- MFMA MLP-1 (262->64) fused with MLP-2 (64->10) ----------------

__global__ __launch_bounds__(256) void k_mlp1f(
    const unsigned short* __restrict__ xb, const unsigned short* __restrict__ w1t,
    const float* __restrict__ b1, const float* __restrict__ w2,
    const float* __restrict__ b2, float* __restrict__ out) {
    __shared__ float w2l[64][10];
    __shared__ float b2l[10];
    __shared__ float b1l[64];
    for (int t = threadIdx.x; t < 714; t += 256) {
        if (t < 640) ((float*)w2l)[t] = w2[t];
        else if (t < 650) b2l[t - 640] = b2[t - 640];
        else b1l[t - 650] = b1[t - 650];
    }
    __syncthreads();

    const int w = threadIdx.x >> 6, l = threadIdx.x & 63;
    const int lo = l & 15, hi = l >> 4;
    const int row_w = blockIdx.x * 256 + w * 64;

    f32x4 acc[4][4];
#pragma unroll
    for (int a = 0; a < 4; a++)
#pragma unroll
        for (int b = 0; b < 4; b++) acc[a][b] = (f32x4)0.f;

#pragma unroll
    for (int ks = 0; ks < 9; ks++) {
        const int k0 = ks * 32 + hi * 8;
        s16x8 bf[4];
#pragma unroll
        for (int ct = 0; ct < 4; ct++)
            bf[ct] = *(const s16x8*)(w1t + (size_t)(ct * 16 + lo) * 288 + k0);
#pragma unroll
        for (int rt = 0; rt < 4; rt++) {
            s16x8 af = *(const s16x8*)(xb + (size_t)(row_w + rt * 16 + lo) * XSB + k0);
#pragma unroll
            for (int ct = 0; ct < 4; ct++)
                acc[rt][ct] = __builtin_amdgcn_mfma_f32_16x16x32_bf16(af, bf[ct], acc[rt][ct], 0, 0, 0);
        }
    }

#pragma unroll
    for (int rt = 0; rt < 4; rt++) {
#pragma unroll
        for (int r = 0; r < 4; r++) {
            int node = row_w + rt * 16 + hi * 4 + r;
            float po[10];
#pragma unroll
            for (int o = 0; o < 10; o++) po[o] = 0.f;
#pragma unroll
            for (int ct = 0; ct < 4; ct++) {
                int c = ct * 16 + lo;
                float hv = acc[rt][ct][r] + b1l[c];
#pragma unroll
                for (int o = 0; o < 10; o++) po[o] = fmaf(hv, w2l[c][o], po[o]);
            }
#pragma unroll
            for (int m = 1; m < 16; m <<= 1)
#pragma unroll
                for (int o = 0; o < 10; o++) po[o] += __shfl_xor(po[o], m);
            if (lo == 0 && node < NN) {
                float* op = out + (size_t)node * 10;
#pragma unroll
                for (int o = 0; o < 5; o++)
                    *(float2*)(op + o * 2) = make_float2(po[o * 2] + b2l[o * 2],
                                                         po[o * 2 + 1] + b2l[o * 2 + 1]);
            }
        }
    }
}

// ---------------- edge aggregation: bf16 gather-sum, fp32 accumulate ----------------
// Lane group g = l>>4 handles edges p0+g, p0+4+g; lane lg = l&15 owns channels
// 4lg..4lg+3 via one 16B gather of packed bf16 (P, PG). Unpack = 2 bit-ops, then
// 2 fp32 adds per channel. Clamped slots gather the all-zero dummy row.

template <int RELU>
__global__ __launch_bounds__(256) void k_edge(
    const uint4* __restrict__ vg,     // [NN+1][16] uint4 = 64 channels of bf16(P)|bf16(PG)<<16
    const uint2* __restrict__ qh,     // [NN][16] uint2 = 64 channels of half q
    const int* __restrict__ rowptr, const int* __restrict__ csrc,
    unsigned short* __restrict__ xb, int col) {
    int node = blockIdx.x * 4 + (threadIdx.x >> 6);
    int l = threadIdx.x & 63;
    int g = l >> 4, lg = l & 15;
    if (node >= NN) return;
    int b = rowptr[node], e = rowptr[node + 1];
    uint2 qr = qh[(size_t)node * 16 + lg];       // prefetch
    float d[4] = {0.f, 0.f, 0.f, 0.f};
    float s[4] = {0.f, 0.f, 0.f, 0.f};
    for (int p0 = b; p0 < e; p0 += 8) {
        int pp0 = p0 + g, pp1 = p0 + 4 + g;
        int c0 = csrc[min(pp0, e - 1)];
        int c1 = csrc[min(pp1, e - 1)];
        int i0 = (pp0 < e) ? c0 : NN;
        int i1 = (pp1 < e) ? c1 : NN;
        uint4 r0 = vg[(size_t)i0 * 16 + lg];
        uint4 r1 = vg[(size_t)i1 * 16 + lg];
        const unsigned* u0 = (const unsigned*)&r0;
        const unsigned* u1 = (const unsigned*)&r1;
#pragma unroll
        for (int ch = 0; ch < 4; ch++) {
            d[ch] += __uint_as_float(u0[ch] << 16);
            s[ch] += __uint_as_float(u0[ch] & 0xFFFF0000u);
        }
#pragma unroll
        for (int ch = 0; ch < 4; ch++) {
            d[ch] += __uint_as_float(u1[ch] << 16);
            s[ch] += __uint_as_float(u1[ch] & 0xFFFF0000u);
        }
    }
#pragma unroll
    for (int ch = 0; ch < 4; ch++) {
        d[ch] += __shfl_xor(d[ch], 16); s[ch] += __shfl_xor(s[ch], 16);
        d[ch] += __shfl_xor(d[ch], 32); s[ch] += __shfl_xor(s[ch], 32);
    }
    if (g == 0) {
        float2 q01 = __half22float2(*(const __half2*)&qr.x);
        float2 q23 = __half22float2(*(const __half2*)&qr.y);
        float qv[4] = {q01.x, q01.y, q23.x, q23.y};
        float o[4];
#pragma unroll
        for (int ch = 0; ch < 4; ch++) {
            float v = (s[ch] + qv[ch] * d[ch]) / (d[ch] + 1e-16f);
            if (RELU) v = (v > 0.f) ? v : 0.01f * v;
            o[ch] = v;
        }
        unsigned short* dst = xb + (size_t)node * XSB + col + 4 * lg;
        *(unsigned*)(dst)     = (unsigned)f2b(o[0]) | ((unsigned)f2b(o[1]) << 16);
        *(unsigned*)(dst + 2) = (unsigned)f2b(o[2]) | ((unsigned)f2b(o[3]) << 16);
    }
}

// ---------------- launch ----------------

extern "C" void kernel_launch(void* const* d_in, const int* in_sizes, int n_in,
                              void* d_out, int out_size, void* d_ws, size_t ws_size,
                              hipStream_t stream) {
    const float* x = (const float*)d_in[0];
    const int* ei = (const int*)d_in[1];
    const float* W[4][4];
    const float* BP[4];
    int base = 2;
    for (int l = 0; l < 4; l++) {
        for (int m = 0; m < 4; m++) W[l][m] = (const float*)d_in[base + m];
        BP[l] = (const float*)d_in[base + 4];
        base += 5;
    }
    const float* w1 = (const float*)d_in[22];
    const float* b1 = (const float*)d_in[23];
    const float* w2 = (const float*)d_in[24];
    const float* b2 = (const float*)d_in[25];

    char* wsp = (char*)d_ws;
    size_t off = 0;
    auto alloc = [&](size_t bytes) {
        void* p = wsp + off;
        off += (bytes + 255) & ~(size_t)255;
        return p;
    };
    unsigned short* xb = (unsigned short*)alloc((size_t)(NN + 256) * XSB * 2);
    unsigned* vg = (unsigned*)alloc((size_t)(NN + 1) * 64 * 4);   // +1 dummy row
    __half* qh = (__half*)alloc((size_t)NN * 64 * 2);
    int* deg = (int*)alloc((size_t)NN * 4);
    int* rowptr = (int*)alloc((size_t)(NN + 1) * 4);
    int* cursor = (int*)alloc((size_t)NN * 4);
    int* bsum = (int*)alloc(1024 * 4);
    int* csrc = (int*)alloc((size_t)EE * 4);
    const int KPv[4] = {32, 96, 160, 224};
    unsigned short* wt[4];
    for (int l = 0; l < 4; l++) wt[l] = (unsigned short*)alloc((size_t)192 * KPv[l] * 2);
    unsigned short* w1t = (unsigned short*)alloc((size_t)64 * 288 * 2);

    hipMemsetAsync(deg, 0, (size_t)NN * 4, stream);
    k_setup<<<(O7 + 255) / 256, 256, 0, stream>>>(
        x, ei, W[0][0], W[0][1], W[0][3], W[1][0], W[1][1], W[1][3],
        W[2][0], W[2][1], W[2][3], W[3][0], W[3][1], W[3][3], w1,
        xb, wt[0], wt[1], wt[2], wt[3], w1t, deg, vg);

    int nb = (NN + SCAN_B - 1) / SCAN_B;  // 49
    k_scan1<<<nb, 256, 0, stream>>>(deg, rowptr, bsum);
    k_scan3m<<<nb, 256, 0, stream>>>(deg, rowptr, bsum, cursor);
    k_scatter<<<(EE + 255) / 256, 256, 0, stream>>>(ei, cursor, csrc);

    const int gProj = (NN + 127) / 128;  // 782
    const int gEdge = (NN + 3) / 4;      // 25000
    const uint4* vgu = (const uint4*)vg;
    const uint2* qh2 = (const uint2*)qh;

    k_projm<32><<<gProj, 256, 0, stream>>>(xb, wt[0], BP[0], vg, qh);
    k_edge<0><<<gEdge, 256, 0, stream>>>(vgu, qh2, rowptr, csrc, xb, 6);
    k_projm<96><<<gProj, 256, 0, stream>>>(xb, wt[1], BP[1], vg, qh);
    k_edge<1><<<gEdge, 256, 0, stream>>>(vgu, qh2, rowptr, csrc, xb, 70);
    k_projm<160><<<gProj, 256, 0, stream>>>(xb, wt[2], BP[2], vg, qh);
    k_edge<1><<<gEdge, 256, 0, stream>>>(vgu, qh2, rowptr, csrc, xb, 134);
    k_projm<224><<<gProj, 256, 0, stream>>>(xb, wt[3], BP[3], vg, qh);
    k_edge<1><<<gEdge, 256, 0, stream>>>(vgu, qh2, rowptr, csrc, xb, 198);

    k_mlp1f<<<(NN + 255) / 256, 256, 0, stream>>>(xb, w1t, b1, w2, b2, (float*)d_out);
}

// Round 11
// 314.807 us; speedup vs baseline: 1.1232x; 1.0279x over previous
//
#include <hip/hip_runtime.h>
#include <hip/hip_fp16.h>

#define NN 100000
#define EE 600000
#define XSB 288          // bf16 feature row stride (262 used, 64B-aligned rows)
#define SCAN_B 2048
#define LOG2E 1.44269504f

typedef __attribute__((ext_vector_type(8))) short s16x8;
typedef __attribute__((ext_vector_type(4))) float f32x4;

__device__ inline unsigned short f2b(float f) {   // fp32 -> bf16 RNE
    unsigned u = __float_as_uint(f);
    u += 0x7fffu + ((u >> 16) & 1u);
    return (unsigned short)(u >> 16);
}

// wt layout: [KP/32][192][32] (k-chunk, col, k-within-chunk), zero-padded k>=fin.
// cols 0-63 = lin, 64-127 = src, 128-191 = pos. (a_dst dead: softmax shift-invariance)
__device__ inline void wconv_elem(int idx, int fin,
                                  const float* wlin, const float* wsrc,
                                  const float* wpos, unsigned short* wt) {
    int ks = idx / 6144;          // 192*32
    int rem = idx - ks * 6144;
    int col = rem >> 5, kk = rem & 31;
    int k = ks * 32 + kk;
    float val = 0.f;
    if (k < fin) {
        int m = col >> 6, c = col & 63;
        const float* W = (m == 0) ? wlin : (m == 1) ? wsrc : wpos;
        val = W[k * 64 + c];
    }
    wt[idx] = f2b(val);
}

// ---------------- fused setup: init xb + weight conversions + degree histogram + dummy row ----
// deg is zeroed by hipMemsetAsync BEFORE this kernel (stream-ordered).
#define O0 600000
#define O1 606144
#define O2 624576
#define O3 655296
#define O4 698304
#define O5 716736
#define O6 1316736
#define O7 1316800       // +64: dummy vg row NN = (P=0, PG=0) -> contributes nothing

__global__ __launch_bounds__(256) void k_setup(
    const float* __restrict__ x, const int* __restrict__ ei,
    const float* __restrict__ wl0, const float* __restrict__ ws0, const float* __restrict__ wp0,
    const float* __restrict__ wl1, const float* __restrict__ ws1, const float* __restrict__ wp1,
    const float* __restrict__ wl2, const float* __restrict__ ws2, const float* __restrict__ wp2,
    const float* __restrict__ wl3, const float* __restrict__ ws3, const float* __restrict__ wp3,
    const float* __restrict__ w1,
    unsigned short* __restrict__ xb,
    unsigned short* __restrict__ wt0, unsigned short* __restrict__ wt1,
    unsigned short* __restrict__ wt2, unsigned short* __restrict__ wt3,
    unsigned short* __restrict__ w1t, int* __restrict__ deg,
    unsigned* __restrict__ vgu) {
    int i = blockIdx.x * 256 + threadIdx.x;
    if (i < O0) {
        int n = i / 6, c = i - n * 6;
        xb[(size_t)n * XSB + c] = f2b(x[i]);
    } else if (i < O1) {
        wconv_elem(i - O0, 6, wl0, ws0, wp0, wt0);
    } else if (i < O2) {
        wconv_elem(i - O1, 70, wl1, ws1, wp1, wt1);
    } else if (i < O3) {
        wconv_elem(i - O2, 134, wl2, ws2, wp2, wt2);
    } else if (i < O4) {
        wconv_elem(i - O3, 198, wl3, ws3, wp3, wt3);
    } else if (i < O5) {
        int idx = i - O4;                 // 64*288
        int col = idx / 288, k = idx - col * 288;
        w1t[idx] = f2b((k < 262) ? w1[k * 64 + col] : 0.f);
    } else if (i < O6) {
        atomicAdd(&deg[ei[EE + (i - O5)]], 1);   // dst-degree histogram
    } else if (i < O7) {
        vgu[(size_t)NN * 64 + (i - O6)] = 0u;    // dummy row: (P,PG) = (0,0)
    }
}

// ---------------- CSR build ----------------

__global__ void k_scan1(const int* __restrict__ deg, int* __restrict__ rowptr,
                        int* __restrict__ bsum) {
    __shared__ int sh[256];
    int b = blockIdx.x, t = threadIdx.x;
    int base = b * SCAN_B + t * 8;
    int vals[8];
    int s = 0;
#pragma unroll
    for (int j = 0; j < 8; j++) {
        int i = base + j;
        int d = (i < NN) ? deg[i] : 0;
        s += d;
        vals[j] = s;
    }
    sh[t] = s;
    __syncthreads();
    for (int off = 1; off < 256; off <<= 1) {
        int vv = (t >= off) ? sh[t - off] : 0;
        __syncthreads();
        sh[t] += vv;
        __syncthreads();
    }
    int excl = (t > 0) ? sh[t - 1] : 0;
#pragma unroll
    for (int j = 0; j < 8; j++) {
        int i = base + j;
        if (i < NN) rowptr[i + 1] = vals[j] + excl;
    }
    if (t == 255) bsum[b] = sh[255];     // raw per-block total
}

// merged scan2+scan3: each block wave-reduces its own prefix of bsum (nb<=64)
__global__ void k_scan3m(const int* __restrict__ deg, int* __restrict__ rowptr,
                         const int* __restrict__ bsum, int* __restrict__ cursor) {
    __shared__ int soff;
    int b = blockIdx.x, t = threadIdx.x;
    if (t < 64) {
        int v = (t < b) ? bsum[t] : 0;   // nb = 49 <= 64
#pragma unroll
        for (int m = 1; m < 64; m <<= 1) v += __shfl_xor(v, m);
        if (t == 0) soff = v;
    }
    __syncthreads();
    int off = soff;
    int base = b * SCAN_B + t * 8;
#pragma unroll
    for (int j = 0; j < 8; j++) {
        int i = base + j;
        if (i < NN) {
            int incl = rowptr[i + 1] + off;
            rowptr[i + 1] = incl;
            cursor[i] = incl - deg[i];
        }
    }
    if (b == 0 && t == 0) rowptr[0] = 0;
}

__global__ void k_scatter(const int* __restrict__ ei, int* __restrict__ cursor,
                          int* __restrict__ csrc) {
    int e = blockIdx.x * 256 + threadIdx.x;
    if (e < EE) {
        int d = ei[EE + e];
        int pos = atomicAdd(&cursor[d], 1);
        csrc[pos] = ei[e];
    }
}

// ---------------- MFMA 3-way projection, LDS-staged weights ----------------
// The softmax numerator exp(-v) depends only on the SOURCE node, so precompute
// P = 2^(-(a_src+p)*log2e) and PG = P*(h-p), packed as TWO BF16 in one uint32
// (bf16 has fp32 exponent range: e^+-25 cannot overflow/underflow, unlike fp16).
// qh[node][c] = half(p + b_pos).

template <int KP>
__global__ __launch_bounds__(256) void k_projm(
    const unsigned short* __restrict__ xb, const unsigned short* __restrict__ wt,
    const float* __restrict__ bpos,
    unsigned* __restrict__ vg, __half* __restrict__ qh) {
    __shared__ short wl[192 * 32];
    const int t = threadIdx.x;
    const int w = t >> 6, l = t & 63;
    const int lo = l & 15, hi = l >> 4;
    const int row_w = blockIdx.x * 128 + w * 32;

    f32x4 acc[2][12];
#pragma unroll
    for (int a = 0; a < 2; a++)
#pragma unroll
        for (int i = 0; i < 12; i++) acc[a][i] = (f32x4)0.f;

    const unsigned short* arow0 = xb + (size_t)(row_w + lo) * XSB;
    const unsigned short* arow1 = xb + (size_t)(row_w + 16 + lo) * XSB;
#pragma unroll
    for (int ks = 0; ks < KP / 32; ks++) {
        __syncthreads();
        {
            const uint4* src = (const uint4*)wt + (size_t)ks * 768;
            uint4* dst = (uint4*)wl;
#pragma unroll
            for (int i = 0; i < 3; i++) dst[i * 256 + t] = src[i * 256 + t];
        }
        __syncthreads();
        s16x8 af0 = *(const s16x8*)(arow0 + ks * 32 + hi * 8);
        s16x8 af1 = *(const s16x8*)(arow1 + ks * 32 + hi * 8);
#pragma unroll
        for (int ct = 0; ct < 12; ct++) {
            s16x8 bf = *(const s16x8*)&wl[(ct * 16 + lo) * 32 + hi * 8];
            acc[0][ct] = __builtin_amdgcn_mfma_f32_16x16x32_bf16(af0, bf, acc[0][ct], 0, 0, 0);
            acc[1][ct] = __builtin_amdgcn_mfma_f32_16x16x32_bf16(af1, bf, acc[1][ct], 0, 0, 0);
        }
    }

#pragma unroll
    for (int tile = 0; tile < 2; tile++) {
#pragma unroll
        for (int r = 0; r < 4; r++) {
            int node = row_w + tile * 16 + hi * 4 + r;
            if (node < NN) {
#pragma unroll
                for (int j = 0; j < 4; j++) {
                    int c = j * 16 + lo;
                    float h  = acc[tile][0 + j][r];
                    float as = acc[tile][4 + j][r];
                    float p  = acc[tile][8 + j][r];
                    size_t o = (size_t)node * 64 + c;
                    float P = __builtin_amdgcn_exp2f(-(as + p) * LOG2E);
                    vg[o] = (unsigned)f2b(P) | ((unsigned)f2b(P * (h - p)) << 16);
                    qh[o] = __float2half(p + bpos[c]);
                }
            }
        }
    }
}

// ---------------- MFMA MLP-1 (262->64) fused with MLP-2 (64->10) ----------------

__global__ __launch_bounds__(256) void k_mlp1f(
    const unsigned short* __restrict__ xb, const unsigned short* __restrict__ w1t,
    const float* __restrict__ b1, const float* __restrict__ w2,
    const float* __restrict__ b2, float* __restrict__ out) {
    __shared__ float w2l[64][10];
    __shared__ float b2l[10];
    __shared__ float b1l[64];
    for (int t = threadIdx.x; t < 714; t += 256) {
        if (t < 640) ((float*)w2l)[t] = w2[t];
        else if (t < 650) b2l[t - 640] = b2[t - 640];
        else b1l[t - 650] = b1[t - 650];
    }
    __syncthreads();

    const int w = threadIdx.x >> 6, l = threadIdx.x & 63;
    const int lo = l & 15, hi = l >> 4;
    const int row_w = blockIdx.x * 256 + w * 64;

    f32x4 acc[4][4];
#pragma unroll
    for (int a = 0; a < 4; a++)
#pragma unroll
        for (int b = 0; b < 4; b++) acc[a][b] = (f32x4)0.f;

#pragma unroll
    for (int ks = 0; ks < 9; ks++) {
        const int k0 = ks * 32 + hi * 8;
        s16x8 bf[4];
#pragma unroll
        for (int ct = 0; ct < 4; ct++)
            bf[ct] = *(const s16x8*)(w1t + (size_t)(ct * 16 + lo) * 288 + k0);
#pragma unroll
        for (int rt = 0; rt < 4; rt++) {
            s16x8 af = *(const s16x8*)(xb + (size_t)(row_w + rt * 16 + lo) * XSB + k0);
#pragma unroll
            for (int ct = 0; ct < 4; ct++)
                acc[rt][ct] = __builtin_amdgcn_mfma_f32_16x16x32_bf16(af, bf[ct], acc[rt][ct], 0, 0, 0);
        }
    }

#pragma unroll
    for (int rt = 0; rt < 4; rt++) {
#pragma unroll
        for (int r = 0; r < 4; r++) {
            int node = row_w + rt * 16 + hi * 4 + r;
            float po[10];
#pragma unroll
            for (int o = 0; o < 10; o++) po[o] = 0.f;
#pragma unroll
            for (int ct = 0; ct < 4; ct++) {
                int c = ct * 16 + lo;
                float hv = acc[rt][ct][r] + b1l[c];
#pragma unroll
                for (int o = 0; o < 10; o++) po[o] = fmaf(hv, w2l[c][o], po[o]);
            }
#pragma unroll
            for (int m = 1; m < 16; m <<= 1)
#pragma unroll
                for (int o = 0; o < 10; o++) po[o] += __shfl_xor(po[o], m);
            if (lo == 0 && node < NN) {
                float* op = out + (size_t)node * 10;
#pragma unroll
                for (int o = 0; o < 5; o++)
                    *(float2*)(op + o * 2) = make_float2(po[o * 2] + b2l[o * 2],
                                                         po[o * 2 + 1] + b2l[o * 2 + 1]);
            }
        }
    }
}

// ---------------- edge aggregation: group-per-node bf16 gather-sum ----------------
// Wave = 4 nodes: 16-lane group g owns node wave*4+g; lane lg owns channels
// 4lg..4lg+3 (group-local accumulation, NO cross-group reduce). Edge loop 2-way
// unrolled: up to 8 independent 256B gathers in flight per wave across iterations.
// Slots past a group's degree gather the all-zero dummy row NN.

template <int RELU>
__global__ __launch_bounds__(256) void k_edge(
    const uint4* __restrict__ vg,     // [NN+1][16] uint4 = 64 channels of bf16(P)|bf16(PG)<<16
    const uint2* __restrict__ qh,     // [NN][16] uint2 = 64 channels of half q
    const int* __restrict__ rowptr, const int* __restrict__ csrc,
    unsigned short* __restrict__ xb, int col) {
    int l = threadIdx.x & 63;
    int g = l >> 4, lg = l & 15;
    int node = (blockIdx.x * 4 + (threadIdx.x >> 6)) * 4 + g;   // NN % 16 == 0: always < NN
    int b = rowptr[node], e = rowptr[node + 1];
    int deg = e - b;
    int md = max(deg, __shfl_xor(deg, 16));      // max degree over the wave's 4 groups
    md = max(md, __shfl_xor(md, 32));
    uint2 qr = qh[(size_t)node * 16 + lg];       // prefetch
    float d[4] = {0.f, 0.f, 0.f, 0.f};
    float s[4] = {0.f, 0.f, 0.f, 0.f};
    for (int it = 0; it < md; it += 2) {
        int i0 = NN, i1 = NN;
        if (it < deg)     i0 = csrc[b + it];
        if (it + 1 < deg) i1 = csrc[b + it + 1];
        uint4 r0 = vg[(size_t)i0 * 16 + lg];
        uint4 r1 = vg[(size_t)i1 * 16 + lg];
        const unsigned* u0 = (const unsigned*)&r0;
        const unsigned* u1 = (const unsigned*)&r1;
#pragma unroll
        for (int ch = 0; ch < 4; ch++) {
            d[ch] += __uint_as_float(u0[ch] << 16);
            s[ch] += __uint_as_float(u0[ch] & 0xFFFF0000u);
        }
#pragma unroll
        for (int ch = 0; ch < 4; ch++) {
            d[ch] += __uint_as_float(u1[ch] << 16);
            s[ch] += __uint_as_float(u1[ch] & 0xFFFF0000u);
        }
    }
    float2 q01 = __half22float2(*(const __half2*)&qr.x);
    float2 q23 = __half22float2(*(const __half2*)&qr.y);
    float qv[4] = {q01.x, q01.y, q23.x, q23.y};
    float o[4];
#pragma unroll
    for (int ch = 0; ch < 4; ch++) {
        float v = (s[ch] + qv[ch] * d[ch]) / (d[ch] + 1e-16f);
        if (RELU) v = (v > 0.f) ? v : 0.01f * v;
        o[ch] = v;
    }
    unsigned short* dst = xb + (size_t)node * XSB + col + 4 * lg;
    *(unsigned*)(dst)     = (unsigned)f2b(o[0]) | ((unsigned)f2b(o[1]) << 16);
    *(unsigned*)(dst + 2) = (unsigned)f2b(o[2]) | ((unsigned)f2b(o[3]) << 16);
}

// ---------------- launch ----------------

extern "C" void kernel_launch(void* const* d_in, const int* in_sizes, int n_in,
                              void* d_out, int out_size, void* d_ws, size_t ws_size,
                              hipStream_t stream) {
    const float* x = (const float*)d_in[0];
    const int* ei = (const int*)d_in[1];
    const float* W[4][4];
    const float* BP[4];
    int base = 2;
    for (int l = 0; l < 4; l++) {
        for (int m = 0; m < 4; m++) W[l][m] = (const float*)d_in[base + m];
        BP[l] = (const float*)d_in[base + 4];
        base += 5;
    }
    const float* w1 = (const float*)d_in[22];
    const float* b1 = (const float*)d_in[23];
    const float* w2 = (const float*)d_in[24];
    const float* b2 = (const float*)d_in[25];

    char* wsp = (char*)d_ws;
    size_t off = 0;
    auto alloc = [&](size_t bytes) {
        void* p = wsp + off;
        off += (bytes + 255) & ~(size_t)255;
        return p;
    };
    unsigned short* xb = (unsigned short*)alloc((size_t)(NN + 256) * XSB * 2);
    unsigned* vg = (unsigned*)alloc((size_t)(NN + 1) * 64 * 4);   // +1 dummy row
    __half* qh = (__half*)alloc((size_t)NN * 64 * 2);
    int* deg = (int*)alloc((size_t)NN * 4);
    int* rowptr = (int*)alloc((size_t)(NN + 1) * 4);
    int* cursor = (int*)alloc((size_t)NN * 4);
    int* bsum = (int*)alloc(1024 * 4);
    int* csrc = (int*)alloc((size_t)EE * 4);
    const int KPv[4] = {32, 96, 160, 224};
    unsigned short* wt[4];
    for (int l = 0; l < 4; l++) wt[l] = (unsigned short*)alloc((size_t)192 * KPv[l] * 2);
    unsigned short* w1t = (unsigned short*)alloc((size_t)64 * 288 * 2);

    hipMemsetAsync(deg, 0, (size_t)NN * 4, stream);
    k_setup<<<(O7 + 255) / 256, 256, 0, stream>>>(
        x, ei, W[0][0], W[0][1], W[0][3], W[1][0], W[1][1], W[1][3],
        W[2][0], W[2][1], W[2][3], W[3][0], W[3][1], W[3][3], w1,
        xb, wt[0], wt[1], wt[2], wt[3], w1t, deg, vg);

    int nb = (NN + SCAN_B - 1) / SCAN_B;  // 49
    k_scan1<<<nb, 256, 0, stream>>>(deg, rowptr, bsum);
    k_scan3m<<<nb, 256, 0, stream>>>(deg, rowptr, bsum, cursor);
    k_scatter<<<(EE + 255) / 256, 256, 0, stream>>>(ei, cursor, csrc);

    const int gProj = (NN + 127) / 128;  // 782
    const int gEdge = NN / 16;           // 6250 (NN % 16 == 0)
    const uint4* vgu = (const uint4*)vg;
    const uint2* qh2 = (const uint2*)qh;

    k_projm<32><<<gProj, 256, 0, stream>>>(xb, wt[0], BP[0], vg, qh);
    k_edge<0><<<gEdge, 256, 0, stream>>>(vgu, qh2, rowptr, csrc, xb, 6);
    k_projm<96><<<gProj, 256, 0, stream>>>(xb, wt[1], BP[1], vg, qh);
    k_edge<1><<<gEdge, 256, 0, stream>>>(vgu, qh2, rowptr, csrc, xb, 70);
    k_projm<160><<<gProj, 256, 0, stream>>>(xb, wt[2], BP[2], vg, qh);
    k_edge<1><<<gEdge, 256, 0, stream>>>(vgu, qh2, rowptr, csrc, xb, 134);
    k_projm<224><<<gProj, 256, 0, stream>>>(xb, wt[3], BP[3], vg, qh);
    k_edge<1><<<gEdge, 256, 0, stream>>>(vgu, qh2, rowptr, csrc, xb, 198);

    k_mlp1f<<<(NN + 255) / 256, 256, 0, stream>>>(xb, w1t, b1, w2, b2, (float*)d_out);
}

// Round 12
// 296.775 us; speedup vs baseline: 1.1914x; 1.0608x over previous
//
#include <hip/hip_runtime.h>
#include <hip/hip_fp16.h>

#define NN 100000
#define EE 600000
#define XSB 288          // bf16 feature row stride (262 used, 64B-aligned rows)
#define SCAN_B 2048
#define LOG2E 1.44269504f

typedef __attribute__((ext_vector_type(8))) short s16x8;
typedef __attribute__((ext_vector_type(4))) float f32x4;

__device__ inline unsigned short f2b(float f) {   // fp32 -> bf16 RNE
    unsigned u = __float_as_uint(f);
    u += 0x7fffu + ((u >> 16) & 1u);
    return (unsigned short)(u >> 16);
}

// wt layout: [KP/32][192][32] (k-chunk, col, k-within-chunk), zero-padded k>=fin.
// cols 0-63 = lin, 64-127 = src, 128-191 = pos. (a_dst dead: softmax shift-invariance)
__device__ inline void wconv_elem(int idx, int fin,
                                  const float* wlin, const float* wsrc,
                                  const float* wpos, unsigned short* wt) {
    int ks = idx / 6144;          // 192*32
    int rem = idx - ks * 6144;
    int col = rem >> 5, kk = rem & 31;
    int k = ks * 32 + kk;
    float val = 0.f;
    if (k < fin) {
        int m = col >> 6, c = col & 63;
        const float* W = (m == 0) ? wlin : (m == 1) ? wsrc : wpos;
        val = W[k * 64 + c];
    }
    wt[idx] = f2b(val);
}

// ---------------- fused setup: init xb + weight conversions + degree histogram + dummy row ----
// deg is zeroed by hipMemsetAsync BEFORE this kernel (stream-ordered).
#define O0 600000
#define O1 606144
#define O2 624576
#define O3 655296
#define O4 698304
#define O5 716736
#define O6 1316736
#define O7 1316800       // +64: dummy vg row NN = (P=0, PG=0) -> contributes nothing

__global__ __launch_bounds__(256) void k_setup(
    const float* __restrict__ x, const int* __restrict__ ei,
    const float* __restrict__ wl0, const float* __restrict__ ws0, const float* __restrict__ wp0,
    const float* __restrict__ wl1, const float* __restrict__ ws1, const float* __restrict__ wp1,
    const float* __restrict__ wl2, const float* __restrict__ ws2, const float* __restrict__ wp2,
    const float* __restrict__ wl3, const float* __restrict__ ws3, const float* __restrict__ wp3,
    const float* __restrict__ w1,
    unsigned short* __restrict__ xb,
    unsigned short* __restrict__ wt0, unsigned short* __restrict__ wt1,
    unsigned short* __restrict__ wt2, unsigned short* __restrict__ wt3,
    unsigned short* __restrict__ w1t, int* __restrict__ deg,
    unsigned* __restrict__ vgu) {
    int i = blockIdx.x * 256 + threadIdx.x;
    if (i < O0) {
        int n = i / 6, c = i - n * 6;
        xb[(size_t)n * XSB + c] = f2b(x[i]);
    } else if (i < O1) {
        wconv_elem(i - O0, 6, wl0, ws0, wp0, wt0);
    } else if (i < O2) {
        wconv_elem(i - O1, 70, wl1, ws1, wp1, wt1);
    } else if (i < O3) {
        wconv_elem(i - O2, 134, wl2, ws2, wp2, wt2);
    } else if (i < O4) {
        wconv_elem(i - O3, 198, wl3, ws3, wp3, wt3);
    } else if (i < O5) {
        int idx = i - O4;                 // 64*288
        int col = idx / 288, k = idx - col * 288;
        w1t[idx] = f2b((k < 262) ? w1[k * 64 + col] : 0.f);
    } else if (i < O6) {
        atomicAdd(&deg[ei[EE + (i - O5)]], 1);   // dst-degree histogram
    } else if (i < O7) {
        vgu[(size_t)NN * 64 + (i - O6)] = 0u;    // dummy row: (P,PG) = (0,0)
    }
}

// ---------------- CSR build ----------------

__global__ void k_scan1(const int* __restrict__ deg, int* __restrict__ rowptr,
                        int* __restrict__ bsum) {
    __shared__ int sh[256];
    int b = blockIdx.x, t = threadIdx.x;
    int base = b * SCAN_B + t * 8;
    int vals[8];
    int s = 0;
#pragma unroll
    for (int j = 0; j < 8; j++) {
        int i = base + j;
        int d = (i < NN) ? deg[i] : 0;
        s += d;
        vals[j] = s;
    }
    sh[t] = s;
    __syncthreads();
    for (int off = 1; off < 256; off <<= 1) {
        int vv = (t >= off) ? sh[t - off] : 0;
        __syncthreads();
        sh[t] += vv;
        __syncthreads();
    }
    int excl = (t > 0) ? sh[t - 1] : 0;
#pragma unroll
    for (int j = 0; j < 8; j++) {
        int i = base + j;
        if (i < NN) rowptr[i + 1] = vals[j] + excl;
    }
    if (t == 255) bsum[b] = sh[255];     // raw per-block total
}

// merged scan2+scan3: each block wave-reduces its own prefix of bsum (nb<=64)
__global__ void k_scan3m(const int* __restrict__ deg, int* __restrict__ rowptr,
                         const int* __restrict__ bsum, int* __restrict__ cursor) {
    __shared__ int soff;
    int b = blockIdx.x, t = threadIdx.x;
    if (t < 64) {
        int v = (t < b) ? bsum[t] : 0;   // nb = 49 <= 64
#pragma unroll
        for (int m = 1; m < 64; m <<= 1) v += __shfl_xor(v, m);
        if (t == 0) soff = v;
    }
    __syncthreads();
    int off = soff;
    int base = b * SCAN_B + t * 8;
#pragma unroll
    for (int j = 0; j < 8; j++) {
        int i = base + j;
        if (i < NN) {
            int incl = rowptr[i + 1] + off;
            rowptr[i + 1] = incl;
            cursor[i] = incl - deg[i];
        }
    }
    if (b == 0 && t == 0) rowptr[0] = 0;
}

__global__ void k_scatter(const int* __restrict__ ei, int* __restrict__ cursor,
                          int* __restrict__ csrc) {
    int e = blockIdx.x * 256 + threadIdx.x;
    if (e < EE) {
        int d = ei[EE + e];
        int pos = atomicAdd(&cursor[d], 1);
        csrc[pos] = ei[e];
    }
}

// ---------------- MFMA 3-way projection, LDS-staged weights ----------------
// The softmax numerator exp(-v) depends only on the SOURCE node, so precompute
// P = 2^(-(a_src+p)*log2e) and PG = P*(h-p), packed as TWO BF16 in one uint32
// (bf16 has fp32 exponent range: e^+-25 cannot overflow/underflow, unlike fp16).
// qh[node][c] = half(p + b_pos).

template <int KP>
__global__ __launch_bounds__(256) void k_projm(
    const unsigned short* __restrict__ xb, const unsigned short* __restrict__ wt,
    const float* __restrict__ bpos,
    unsigned* __restrict__ vg, __half* __restrict__ qh) {
    __shared__ short wl[192 * 32];
    const int t = threadIdx.x;
    const int w = t >> 6, l = t & 63;
    const int lo = l & 15, hi = l >> 4;
    const int row_w = blockIdx.x * 128 + w * 32;

    f32x4 acc[2][12];
#pragma unroll
    for (int a = 0; a < 2; a++)
#pragma unroll
        for (int i = 0; i < 12; i++) acc[a][i] = (f32x4)0.f;

    const unsigned short* arow0 = xb + (size_t)(row_w + lo) * XSB;
    const unsigned short* arow1 = xb + (size_t)(row_w + 16 + lo) * XSB;
#pragma unroll
    for (int ks = 0; ks < KP / 32; ks++) {
        __syncthreads();
        {
            const uint4* src = (const uint4*)wt + (size_t)ks * 768;
            uint4* dst = (uint4*)wl;
#pragma unroll
            for (int i = 0; i < 3; i++) dst[i * 256 + t] = src[i * 256 + t];
        }
        __syncthreads();
        s16x8 af0 = *(const s16x8*)(arow0 + ks * 32 + hi * 8);
        s16x8 af1 = *(const s16x8*)(arow1 + ks * 32 + hi * 8);
#pragma unroll
        for (int ct = 0; ct < 12; ct++) {
            s16x8 bf = *(const s16x8*)&wl[(ct * 16 + lo) * 32 + hi * 8];
            acc[0][ct] = __builtin_amdgcn_mfma_f32_16x16x32_bf16(af0, bf, acc[0][ct], 0, 0, 0);
            acc[1][ct] = __builtin_amdgcn_mfma_f32_16x16x32_bf16(af1, bf, acc[1][ct], 0, 0, 0);
        }
    }

#pragma unroll
    for (int tile = 0; tile < 2; tile++) {
#pragma unroll
        for (int r = 0; r < 4; r++) {
            int node = row_w + tile * 16 + hi * 4 + r;
            if (node < NN) {
#pragma unroll
                for (int j = 0; j < 4; j++) {
                    int c = j * 16 + lo;
                    float h  = acc[tile][0 + j][r];
                    float as = acc[tile][4 + j][r];
                    float p  = acc[tile][8 + j][r];
                    size_t o = (size_t)node * 64 + c;
                    float P = __builtin_amdgcn_exp2f(-(as + p) * LOG2E);
                    vg[o] = (unsigned)f2b(P) | ((unsigned)f2b(P * (h - p)) << 16);
                    qh[o] = __float2half(p + bpos[c]);
                }
            }
        }
    }
}

// ---------------- MFMA MLP-1 (262->64) fused with MLP-2 (64->10) ----------------

__global__ __launch_bounds__(256) void k_mlp1f(
    const unsigned short* __restrict__ xb, const unsigned short* __restrict__ w1t,
    const float* __restrict__ b1, const float* __restrict__ w2,
    const float* __restrict__ b2, float* __restrict__ out) {
    __shared__ float w2l[64][10];
    __shared__ float b2l[10];
    __shared__ float b1l[64];
    for (int t = threadIdx.x; t < 714; t += 256) {
        if (t < 640) ((float*)w2l)[t] = w2[t];
        else if (t < 650) b2l[t - 640] = b2[t - 640];
        else b1l[t - 650] = b1[t - 650];
    }
    __syncthreads();

    const int w = threadIdx.x >> 6, l = threadIdx.x & 63;
    const int lo = l & 15, hi = l >> 4;
    const int row_w = blockIdx.x * 256 + w * 64;

    f32x4 acc[4][4];
#pragma unroll
    for (int a = 0; a < 4; a++)
#pragma unroll
        for (int b = 0; b < 4; b++) acc[a][b] = (f32x4)0.f;

#pragma unroll
    for (int ks = 0; ks < 9; ks++) {
        const int k0 = ks * 32 + hi * 8;
        s16x8 bf[4];
#pragma unroll
        for (int ct = 0; ct < 4; ct++)
            bf[ct] = *(const s16x8*)(w1t + (size_t)(ct * 16 + lo) * 288 + k0);
#pragma unroll
        for (int rt = 0; rt < 4; rt++) {
            s16x8 af = *(const s16x8*)(xb + (size_t)(row_w + rt * 16 + lo) * XSB + k0);
#pragma unroll
            for (int ct = 0; ct < 4; ct++)
                acc[rt][ct] = __builtin_amdgcn_mfma_f32_16x16x32_bf16(af, bf[ct], acc[rt][ct], 0, 0, 0);
        }
    }

#pragma unroll
    for (int rt = 0; rt < 4; rt++) {
#pragma unroll
        for (int r = 0; r < 4; r++) {
            int node = row_w + rt * 16 + hi * 4 + r;
            float po[10];
#pragma unroll
            for (int o = 0; o < 10; o++) po[o] = 0.f;
#pragma unroll
            for (int ct = 0; ct < 4; ct++) {
                int c = ct * 16 + lo;
                float hv = acc[rt][ct][r] + b1l[c];
#pragma unroll
                for (int o = 0; o < 10; o++) po[o] = fmaf(hv, w2l[c][o], po[o]);
            }
#pragma unroll
            for (int m = 1; m < 16; m <<= 1)
#pragma unroll
                for (int o = 0; o < 10; o++) po[o] += __shfl_xor(po[o], m);
            if (lo == 0 && node < NN) {
                float* op = out + (size_t)node * 10;
#pragma unroll
                for (int o = 0; o < 5; o++)
                    *(float2*)(op + o * 2) = make_float2(po[o * 2] + b2l[o * 2],
                                                         po[o * 2 + 1] + b2l[o * 2 + 1]);
            }
        }
    }
}

// ---------------- edge aggregation: group-per-node, preloaded indices ----------------
// Wave = 4 nodes: 16-lane group g owns node wave*4+g; lane lg owns channels 4lg..4lg+3.
// The group's source list (deg<=16 covers 99.994% of Poisson(6)) is preloaded in ONE
// csrc load (lane lg holds edge slot lg); the loop broadcasts indices via register
// shfl and issues 4 independent 256B gathers per iteration -- no dependent load chain.
// Guarded slots gather the all-zero dummy row NN (single hot cacheline).

template <int RELU>
__global__ __launch_bounds__(256) void k_edge(
    const uint4* __restrict__ vg,     // [NN+1][16] uint4 = 64 channels of bf16(P)|bf16(PG)<<16
    const uint2* __restrict__ qh,     // [NN][16] uint2 = 64 channels of half q
    const int* __restrict__ rowptr, const int* __restrict__ csrc,
    unsigned short* __restrict__ xb, int col) {
    int l = threadIdx.x & 63;
    int g = l >> 4, lg = l & 15, gbase = g * 16;
    int node = (blockIdx.x * 4 + (threadIdx.x >> 6)) * 4 + g;   // NN % 16 == 0: always < NN
    int b = rowptr[node], e = rowptr[node + 1];
    int deg = e - b;
    int pre = (deg > 0) ? csrc[min(b + lg, e - 1)] : NN;   // slots 0..15 in one shot
    uint2 qr = qh[(size_t)node * 16 + lg];                 // overlaps with pre load
    float d[4] = {0.f, 0.f, 0.f, 0.f};
    float s[4] = {0.f, 0.f, 0.f, 0.f};

    int it = 0;
    int degc = min(deg, 16);
    for (; it < degc; it += 4) {                           // max it = 12, it+3 = 15
        int i0 = __shfl(pre, gbase + it);
        int i1 = (it + 1 < deg) ? __shfl(pre, gbase + it + 1) : NN;
        int i2 = (it + 2 < deg) ? __shfl(pre, gbase + it + 2) : NN;
        int i3 = (it + 3 < deg) ? __shfl(pre, gbase + it + 3) : NN;
        uint4 r0 = vg[(size_t)i0 * 16 + lg];
        uint4 r1 = vg[(size_t)i1 * 16 + lg];
        uint4 r2 = vg[(size_t)i2 * 16 + lg];
        uint4 r3 = vg[(size_t)i3 * 16 + lg];
        const unsigned* u0 = (const unsigned*)&r0;
        const unsigned* u1 = (const unsigned*)&r1;
        const unsigned* u2 = (const unsigned*)&r2;
        const unsigned* u3 = (const unsigned*)&r3;
#pragma unroll
        for (int ch = 0; ch < 4; ch++) {
            d[ch] += __uint_as_float(u0[ch] << 16);
            s[ch] += __uint_as_float(u0[ch] & 0xFFFF0000u);
            d[ch] += __uint_as_float(u1[ch] << 16);
            s[ch] += __uint_as_float(u1[ch] & 0xFFFF0000u);
            d[ch] += __uint_as_float(u2[ch] << 16);
            s[ch] += __uint_as_float(u2[ch] & 0xFFFF0000u);
            d[ch] += __uint_as_float(u3[ch] << 16);
            s[ch] += __uint_as_float(u3[ch] & 0xFFFF0000u);
        }
    }
    for (; it < deg; ++it) {                               // rare tail: deg > 16
        int i0 = csrc[b + it];
        uint4 r0 = vg[(size_t)i0 * 16 + lg];
        const unsigned* u0 = (const unsigned*)&r0;
#pragma unroll
        for (int ch = 0; ch < 4; ch++) {
            d[ch] += __uint_as_float(u0[ch] << 16);
            s[ch] += __uint_as_float(u0[ch] & 0xFFFF0000u);
        }
    }

    float2 q01 = __half22float2(*(const __half2*)&qr.x);
    float2 q23 = __half22float2(*(const __half2*)&qr.y);
    float qv[4] = {q01.x, q01.y, q23.x, q23.y};
    float o[4];
#pragma unroll
    for (int ch = 0; ch < 4; ch++) {
        float v = (s[ch] + qv[ch] * d[ch]) / (d[ch] + 1e-16f);
        if (RELU) v = (v > 0.f) ? v : 0.01f * v;
        o[ch] = v;
    }
    unsigned short* dst = xb + (size_t)node * XSB + col + 4 * lg;
    *(unsigned*)(dst)     = (unsigned)f2b(o[0]) | ((unsigned)f2b(o[1]) << 16);
    *(unsigned*)(dst + 2) = (unsigned)f2b(o[2]) | ((unsigned)f2b(o[3]) << 16);
}

// ---------------- launch ----------------

extern "C" void kernel_launch(void* const* d_in, const int* in_sizes, int n_in,
                              void* d_out, int out_size, void* d_ws, size_t ws_size,
                              hipStream_t stream) {
    const float* x = (const float*)d_in[0];
    const int* ei = (const int*)d_in[1];
    const float* W[4][4];
    const float* BP[4];
    int base = 2;
    for (int l = 0; l < 4; l++) {
        for (int m = 0; m < 4; m++) W[l][m] = (const float*)d_in[base + m];
        BP[l] = (const float*)d_in[base + 4];
        base += 5;
    }
    const float* w1 = (const float*)d_in[22];
    const float* b1 = (const float*)d_in[23];
    const float* w2 = (const float*)d_in[24];
    const float* b2 = (const float*)d_in[25];

    char* wsp = (char*)d_ws;
    size_t off = 0;
    auto alloc = [&](size_t bytes) {
        void* p = wsp + off;
        off += (bytes + 255) & ~(size_t)255;
        return p;
    };
    unsigned short* xb = (unsigned short*)alloc((size_t)(NN + 256) * XSB * 2);
    unsigned* vg = (unsigned*)alloc((size_t)(NN + 1) * 64 * 4);   // +1 dummy row
    __half* qh = (__half*)alloc((size_t)NN * 64 * 2);
    int* deg = (int*)alloc((size_t)NN * 4);
    int* rowptr = (int*)alloc((size_t)(NN + 1) * 4);
    int* cursor = (int*)alloc((size_t)NN * 4);
    int* bsum = (int*)alloc(1024 * 4);
    int* csrc = (int*)alloc((size_t)(EE + 16) * 4);
    const int KPv[4] = {32, 96, 160, 224};
    unsigned short* wt[4];
    for (int l = 0; l < 4; l++) wt[l] = (unsigned short*)alloc((size_t)192 * KPv[l] * 2);
    unsigned short* w1t = (unsigned short*)alloc((size_t)64 * 288 * 2);

    hipMemsetAsync(deg, 0, (size_t)NN * 4, stream);
    k_setup<<<(O7 + 255) / 256, 256, 0, stream>>>(
        x, ei, W[0][0], W[0][1], W[0][3], W[1][0], W[1][1], W[1][3],
        W[2][0], W[2][1], W[2][3], W[3][0], W[3][1], W[3][3], w1,
        xb, wt[0], wt[1], wt[2], wt[3], w1t, deg, vg);

    int nb = (NN + SCAN_B - 1) / SCAN_B;  // 49
    k_scan1<<<nb, 256, 0, stream>>>(deg, rowptr, bsum);
    k_scan3m<<<nb, 256, 0, stream>>>(deg, rowptr, bsum, cursor);
    k_scatter<<<(EE + 255) / 256, 256, 0, stream>>>(ei, cursor, csrc);

    const int gProj = (NN + 127) / 128;  // 782
    const int gEdge = NN / 16;           // 6250 (NN % 16 == 0)
    const uint4* vgu = (const uint4*)vg;
    const uint2* qh2 = (const uint2*)qh;

    k_projm<32><<<gProj, 256, 0, stream>>>(xb, wt[0], BP[0], vg, qh);
    k_edge<0><<<gEdge, 256, 0, stream>>>(vgu, qh2, rowptr, csrc, xb, 6);
    k_projm<96><<<gProj, 256, 0, stream>>>(xb, wt[1], BP[1], vg, qh);
    k_edge<1><<<gEdge, 256, 0, stream>>>(vgu, qh2, rowptr, csrc, xb, 70);
    k_projm<160><<<gProj, 256, 0, stream>>>(xb, wt[2], BP[2], vg, qh);
    k_edge<1><<<gEdge, 256, 0, stream>>>(vgu, qh2, rowptr, csrc, xb, 134);
    k_projm<224><<<gProj, 256, 0, stream>>>(xb, wt[3], BP[3], vg, qh);
    k_edge<1><<<gEdge, 256, 0, stream>>>(vgu, qh2, rowptr, csrc, xb, 198);

    k_mlp1f<<<(NN + 255) / 256, 256, 0, stream>>>(xb, w1t, b1, w2, b2, (float*)d_out);
}